// Round 9
// baseline (222.618 us; speedup 1.0000x reference)
//
#include <hip/hip_runtime.h>
#include <hip/hip_bf16.h>
#include <stdint.h>

#define M_DIM 16384   // 8 * 2048
#define N_DIM 2048    // OUT_F
#define K_DIM 2048    // IN_F

typedef __attribute__((ext_vector_type(8))) __bf16 bf16x8;
typedef __attribute__((ext_vector_type(4))) float f32x4;

__device__ __forceinline__ unsigned short f2bf(float f) {
  unsigned int u = __builtin_bit_cast(unsigned int, f);
  u += 0x7FFFu + ((u >> 16) & 1u);   // round-to-nearest-even
  return (unsigned short)(u >> 16);
}

__device__ __forceinline__ float sigmoidf_(float x) {
  return 1.0f / (1.0f + __expf(-x));
}

// ---------------- kernel 1: X f32 -> bf16 ----------------
__global__ __launch_bounds__(256) void convert_x(const float4* __restrict__ x,
                                                 uint4* __restrict__ xb) {
  int idx = blockIdx.x * 256 + threadIdx.x;   // one uint4 (8 bf16) per thread
  float4 a = x[idx * 2];
  float4 b = x[idx * 2 + 1];
  uint4 r;
  r.x = (unsigned)f2bf(a.x) | ((unsigned)f2bf(a.y) << 16);
  r.y = (unsigned)f2bf(a.z) | ((unsigned)f2bf(a.w) << 16);
  r.z = (unsigned)f2bf(b.x) | ((unsigned)f2bf(b.y) << 16);
  r.w = (unsigned)f2bf(b.z) | ((unsigned)f2bf(b.w) << 16);
  xb[idx] = r;
}

// ---------------- kernel 2: weight materialization (producer-aligned) -------
// XCD x (blockIdx%8) materializes exactly B panel o in [x*256, x*256+256) --
// the panel GEMM-XCD x reads (B stays dirty-resident in its birth L2).
__global__ __launch_bounds__(256) void make_w(const float4* __restrict__ pw,
                                              const float4* __restrict__ nw,
                                              const float* __restrict__ exps,
                                              const float* __restrict__ maskw,
                                              const float* __restrict__ scale,
                                              unsigned short* __restrict__ wout) {
  const int beta = blockIdx.x;          // 16384 blocks
  const int xcd = beta & 7;
  const int j = beta >> 3;              // 0..2047
  const int o = xcd * 256 + (j >> 3);   // output row (B panel row)
  const int iblk = j & 7;               // 256-wide i chunk
  int idx = (o * 2048 + iblk * 256) + threadIdx.x;   // flat (o*K + i) in float4s
  float4 p = pw[idx];
  float4 n = nw[idx];
  float s = scale[0];
  float c0 = sigmoidf_(maskw[0]) * exps[0] * s;
  float c1 = sigmoidf_(maskw[1]) * exps[1] * s;
  float c2 = sigmoidf_(maskw[2]) * exps[2] * s;
  float c3 = sigmoidf_(maskw[3]) * exps[3] * s;
  float w = (sigmoidf_(p.x) - sigmoidf_(n.x)) * c0
          + (sigmoidf_(p.y) - sigmoidf_(n.y)) * c1
          + (sigmoidf_(p.z) - sigmoidf_(n.z)) * c2
          + (sigmoidf_(p.w) - sigmoidf_(n.w)) * c3;
  wout[idx] = f2bf(w);
}

// ---------------- kernel 3: bias ----------------
__global__ __launch_bounds__(256) void make_bias(const float* __restrict__ pb,
                                                 const float* __restrict__ nb,
                                                 const float* __restrict__ bexps,
                                                 const float* __restrict__ bscale,
                                                 float* __restrict__ bias) {
  int o = blockIdx.x * 256 + threadIdx.x;
  if (o < N_DIM) {
    float x = 0.f;
#pragma unroll
    for (int n = 0; n < 4; ++n) x += (pb[o * 4 + n] - nb[o * 4 + n]) * bexps[n];
    float xc = fminf(fmaxf(x, -1.f), 1.f);
    float mag = rintf(fabsf(xc) * 15.f) * (1.f / 15.f);
    float sgn = (xc > 0.f) ? 1.f : ((xc < 0.f) ? -1.f : 0.f);
    bias[o] = mag * sgn * bscale[0];
  }
}

// ---------------- kernel 4: 256x256 GEMM, BK=32, anti-phase wave roles ------
// R8 post-mortem: all depth/gate variants ~2700cy/iter because the LDS pipe
// (~1400cy: 96 ds_read_b128 + gload writes) and matrix pipe (~1024cy) run
// SERIALLY -- both waves per SIMD are barrier-locked into the same phase and
// each wave's MFMA depends on its own just-issued reads. MfmaUtil 41% ==
// 1024/2700 confirms. Fix: anti-phase roles. X waves {read t; stage; MFMA t},
// Y waves {MFMA t (frags pre-read); stage; read t+1}: X's LDS burst overlaps
// Y's MFMA burst at the WAVE level regardless of compiler scheduling.
// role = (w&1)^((w>>2)&1): one X + one Y per SIMD under both round-robin and
// block wave->SIMD mappings.
//
// Collectivity (re-derived): 4 gload_lds/wave/iter; VMCNT(4) at end of iter t
// leaves only tile t+3's staging outstanding => after each barrier, tiles
// <= t+1 are COLLECTIVELY landed. X reads t, Y reads t+1: both safe. Gate
// slack = 1 full iter (> latency). Prologue stages tiles 0,1,2; VMCNT(4)
// retires 0,1; Y pre-reads tile 0 frags. VMCNT(0) after loop so no DMA is
// outstanding into deallocated LDS.
//
// LDS tile layout (A and B identical): logical (r in [0,256), k in [0,32))
//   fr = r & 127, hi = r >> 7; slot = ((k>>3) + 4*hi) ^ (fr & 7)
//   byte = fr*128 + slot*16. Linear gload dest + inverse-mapped global src
//   (rule 21); reads 8 lanes/16B slot = 2/bank = conflict-free (m136).

#define BM 256
#define BN 256
#define BK 32
#define NT (K_DIM / BK)   // 64
#define NBUF 4

__device__ __forceinline__ void gload16(const void* g, void* l) {
  __builtin_amdgcn_global_load_lds(
      (const __attribute__((address_space(1))) unsigned int*)g,
      (__attribute__((address_space(3))) unsigned int*)l, 16, 0, 0);
}

#define VMCNT(n) asm volatile("s_waitcnt vmcnt(" #n ")" ::: "memory")
#define BAR() __builtin_amdgcn_s_barrier()

__global__ __launch_bounds__(512, 2) void gemm_bias(const unsigned short* __restrict__ X,
                                                    const unsigned short* __restrict__ W,
                                                    const float* __restrict__ bias,
                                                    float* __restrict__ out) {
  __shared__ unsigned short sA[NBUF][128 * 64];   // 4 x 16 KiB
  __shared__ unsigned short sB[NBUF][128 * 64];   // 4 x 16 KiB  (128 KiB total)

  const int tid = threadIdx.x;
  // Locality swizzle (R5, kept): one bn-column per XCD; B panel L2-private.
  const int bn = (int)blockIdx.x & 7;    // == XCD (dispatch round-robin)
  const int bm = (int)blockIdx.x >> 3;   // 0..63
  const int row0 = bm * BM, col0 = bn * BN;

  const int w = tid >> 6, l = tid & 63;
  const int wr = w >> 2;        // 0..1  (M wave group)
  const int wc = w & 3;         // 0..3  (N wave group)
  const int lr = l & 15;
  const int lk4 = l >> 4;       // 0..3
  const int lr7 = lr & 7;
  const int role = (w & 1) ^ ((w >> 2) & 1);   // 0=X read-first, 1=Y mfma-first

  const unsigned short* Ag = X + (size_t)row0 * K_DIM;
  const unsigned short* Bg = W + (size_t)col0 * K_DIM;

  // ---- staging: one gload_lds per thread per round (8KB round, fr rr..rr+63)
  const int s_frl = tid >> 3;                       // 0..63 (fr - rr)
  const int s_pre = (tid & 7) ^ ((tid >> 3) & 7);
  const int s_rglo = 128 * (s_pre >> 2);            // 0 or 128
  const int s_k = (s_pre & 3) * 8;
  const int s_dst = tid * 8;                        // us offset within round

  auto stage = [&](unsigned short* lbase, const unsigned short* gbase,
                   int rr, int tk) {
    gload16(gbase + (size_t)(rr + s_frl + s_rglo) * K_DIM + tk * BK + s_k,
            lbase + rr * 64 + s_dst);
  };

  // ---- fragment reads (conflict-free: 8 lanes per 16B slot = 2/bank)
  auto rdA = [&](const unsigned short* base, int mf) -> bf16x8 {
    int fr = mf * 16 + lr;                   // (wr*128)&127 == 0
    int slot = (lk4 + 4 * wr) ^ lr7;
    return *(const bf16x8*)&base[fr * 64 + slot * 8];
  };
  auto rdB = [&](const unsigned short* base, int nf) -> bf16x8 {
    int fr = (wc & 1) * 64 + nf * 16 + lr;
    int slot = (lk4 + 4 * (wc >> 1)) ^ lr7;
    return *(const bf16x8*)&base[fr * 64 + slot * 8];
  };

  f32x4 acc[8][4] = {};
  bf16x8 a[8], b[4];

#define DO_MFMA()                                                             \
  __builtin_amdgcn_s_setprio(1);                                              \
  _Pragma("unroll") for (int mf = 0; mf < 8; ++mf)                            \
  _Pragma("unroll") for (int nf = 0; nf < 4; ++nf)                            \
      acc[mf][nf] = __builtin_amdgcn_mfma_f32_16x16x32_bf16(                  \
          a[mf], b[nf], acc[mf][nf], 0, 0, 0);                                \
  __builtin_amdgcn_s_setprio(0);

  // ---- prologue: stage tiles 0,1,2 (12 loads/wave in flight)
#pragma unroll
  for (int pt = 0; pt < 3; ++pt) {
    stage(sA[pt], Ag, 0, pt);
    stage(sA[pt], Ag, 64, pt);
    stage(sB[pt], Bg, 0, pt);
    stage(sB[pt], Bg, 64, pt);
  }
  VMCNT(4);   // tiles 0,1 landed (leaves tile 2's 4 loads)
  BAR();

  if (role) {   // Y waves pre-read tile 0 fragments
#pragma unroll
    for (int mf = 0; mf < 8; ++mf) a[mf] = rdA(sA[0], mf);
#pragma unroll
    for (int nf = 0; nf < 4; ++nf) b[nf] = rdB(sB[0], nf);
  }

  for (int t = 0; t < NT; ++t) {
    const unsigned short* pa = sA[t & 3];
    const unsigned short* pb = sB[t & 3];
    const unsigned short* na = sA[(t + 1) & 3];
    const unsigned short* nb = sB[(t + 1) & 3];
    unsigned short* qa = sA[(t + 3) & 3];
    unsigned short* qb = sB[(t + 3) & 3];
    const int tk3 = (t + 3) & (NT - 1);   // wrapped tail: junk into dead buf

    if (role == 0) {
      // X: read tile t; stage t+3; MFMA t
#pragma unroll
      for (int mf = 0; mf < 8; ++mf) a[mf] = rdA(pa, mf);
#pragma unroll
      for (int nf = 0; nf < 4; ++nf) b[nf] = rdB(pb, nf);
      stage(qa, Ag, 0, tk3);
      stage(qa, Ag, 64, tk3);
      stage(qb, Bg, 0, tk3);
      stage(qb, Bg, 64, tk3);
      DO_MFMA();
    } else {
      // Y: MFMA t (fragments read last iter); stage t+3; read tile t+1
      DO_MFMA();
      stage(qa, Ag, 0, tk3);
      stage(qa, Ag, 64, tk3);
      stage(qb, Bg, 0, tk3);
      stage(qb, Bg, 64, tk3);
#pragma unroll
      for (int mf = 0; mf < 8; ++mf) a[mf] = rdA(na, mf);
#pragma unroll
      for (int nf = 0; nf < 4; ++nf) b[nf] = rdB(nb, nf);
    }

    VMCNT(4);   // collective after barrier: tiles <= t+1 landed everywhere
    BAR();
  }
  VMCNT(0);     // drain junk stages: no DMA outstanding into freed LDS

  // ---- epilogue: bias + store (C/D layout: col=lane&15, row=(lane>>4)*4+reg)
  float bv[4];
#pragma unroll
  for (int nf = 0; nf < 4; ++nf) bv[nf] = bias[col0 + wc * 64 + nf * 16 + lr];
  const int orow = lk4 * 4;
#pragma unroll
  for (int mf = 0; mf < 8; ++mf) {
#pragma unroll
    for (int nf = 0; nf < 4; ++nf) {
      const int colg = col0 + wc * 64 + nf * 16 + lr;
#pragma unroll
      for (int r = 0; r < 4; ++r) {
        int rowg = row0 + wr * 128 + mf * 16 + orow + r;
        out[(size_t)rowg * N_DIM + colg] = acc[mf][nf][r] + bv[nf];
      }
    }
  }
#undef DO_MFMA
}

// ---------------- launch ----------------
extern "C" void kernel_launch(void* const* d_in, const int* in_sizes, int n_in,
                              void* d_out, int out_size, void* d_ws, size_t ws_size,
                              hipStream_t stream) {
  const float* input  = (const float*)d_in[0];
  const float* pweight = (const float*)d_in[1];
  const float* nweight = (const float*)d_in[2];
  const float* exps   = (const float*)d_in[3];
  const float* bexps  = (const float*)d_in[4];
  const float* maskw  = (const float*)d_in[5];
  const float* scale  = (const float*)d_in[6];
  const float* pbias  = (const float*)d_in[7];
  const float* nbias  = (const float*)d_in[8];
  const float* bscale = (const float*)d_in[9];
  float* out = (float*)d_out;

  unsigned short* Xb = (unsigned short*)d_ws;                                        // 64 MB
  unsigned short* Wb = (unsigned short*)((char*)d_ws + (size_t)M_DIM * K_DIM * 2);   // 8 MB
  float* bias = (float*)((char*)d_ws + (size_t)M_DIM * K_DIM * 2 + (size_t)N_DIM * K_DIM * 2);

  convert_x<<<(M_DIM * (size_t)K_DIM) / 8 / 256, 256, 0, stream>>>((const float4*)input, (uint4*)Xb);
  make_w<<<((size_t)N_DIM * K_DIM) / 256, 256, 0, stream>>>(
      (const float4*)pweight, (const float4*)nweight, exps, maskw, scale, Wb);
  make_bias<<<(N_DIM + 255) / 256, 256, 0, stream>>>(pbias, nbias, bexps, bscale, bias);

  dim3 grid((M_DIM / BM) * (N_DIM / BN));   // 64 * 8 = 512
  gemm_bias<<<grid, 512, 0, stream>>>(Xb, Wb, bias, out);
}